// Round 2
// baseline (544.909 us; speedup 1.0000x reference)
//
#include <hip/hip_runtime.h>

// ExodusNet: per-timestep dense (32->1) + ExpLeak scan + LIF (SingleSpike,
// MembraneSubtract, norm_input=True). B=32768, F=32, T=100.
// Memory-bound: 419 MB read / 13 MB write -> ~69 us roofline at 6.3 TB/s.
//
// PRECISION CONTRACT (round 1 post-mortem): output is binary spikes, so any
// near-threshold flip costs absmax=1.0. The harness ref (ref=np) is fp32.
// fp64 internals FLIPPED spikes (round 0/1 fail). We must mirror numpy's
// fp32 arithmetic exactly:
//   - dot over f: sequential f=0..31, fp32, separate mul/add rounding
//   - scans: fp32, mul-then-add, NO fma contraction (numpy/XLA don't fuse)
//   - ALPHA = (float)exp(-0.1); OMA = (float)(1.0 - exp(-0.1)) [f64 -> f32]

constexpr int T_STEPS = 100;
constexpr int F_IN    = 32;
constexpr int NB      = 64;            // batches per block
constexpr int BLOCK   = 256;
constexpr int QT      = T_STEPS / 4;   // 25 float4 per time row
constexpr int ROWF    = T_STEPS + 4;   // 104 floats/row: +4 keeps float4 LDS
                                       // writes aligned while breaking the
                                       // 100-float power-of-2-ish stride

__global__ __launch_bounds__(BLOCK) void snn_fused(
    const float* __restrict__ x,   // (B, 32, 100)
    const float* __restrict__ w,   // (1, 32)
    float* __restrict__ out)       // (B, 1, 100)
{
#pragma clang fp contract(off)
    __shared__ float sw[NB * ROWF];   // 26.6 KB: weighted currents

    const int tid = threadIdx.x;
    const long long b0 = (long long)blockIdx.x * NB;

    // Weights are wave-uniform; compiler scalarizes these loads.
    float wf[F_IN];
#pragma unroll
    for (int f = 0; f < F_IN; ++f) wf[f] = w[f];

    // ---- Phase 1: weighted[nb][t] = sum_f x[b0+nb, f, t] * w[f] ----
    // fp32, sequential over f (numpy einsum order: t innermost, f outer),
    // each term separately rounded (contract off => no fma).
    for (int i = tid; i < NB * QT; i += BLOCK) {
        const int nb = i / QT;
        const int j  = i - nb * QT;
        const float* xb = x + (b0 + nb) * (long long)(F_IN * T_STEPS) + 4 * j;
        float a0 = 0.0f, a1 = 0.0f, a2 = 0.0f, a3 = 0.0f;
#pragma unroll
        for (int f = 0; f < F_IN; ++f) {
            const float4 xv = *(const float4*)(xb + f * T_STEPS);
            a0 = a0 + xv.x * wf[f];
            a1 = a1 + xv.y * wf[f];
            a2 = a2 + xv.z * wf[f];
            a3 = a3 + xv.w * wf[f];
        }
        float4* dst = (float4*)(sw + nb * ROWF + 4 * j);
        *dst = make_float4(a0, a1, a2, a3);
    }
    __syncthreads();

    // ---- Phase 2: fused ExpLeak + LIF sequential scan, one thread/batch ----
    // syn[t] = a*syn + i[t];  v[t] = a*v + (1-a)*syn[t];
    // s = (v >= 1);  v -= s  (MembraneSubtract, THR=1). All fp32, no fma.
    if (tid < NB) {
        const double ALPHA64 = 0.90483741803595957316;  // exp(-1/10) in f64
        const float  A   = (float)ALPHA64;
        const float  OMA = (float)(1.0 - ALPHA64);      // f64 sub, then f32 cast
        float syn = 0.0f, v = 0.0f;
        const float* row = sw + tid * ROWF;
        float4* op = (float4*)(out + (b0 + tid) * (long long)T_STEPS);
#pragma unroll
        for (int q = 0; q < QT; ++q) {
            float4 s4;
            float* sp = (float*)&s4;
#pragma unroll
            for (int k = 0; k < 4; ++k) {
                syn = (A * syn) + row[4 * q + k];
                v   = (A * v) + (OMA * syn);
                const float s = (v >= 1.0f) ? 1.0f : 0.0f;
                v = v - s;
                sp[k] = s;
            }
            op[q] = s4;   // per-thread contiguous, 16-B aligned (100%4==0)
        }
    }
}

extern "C" void kernel_launch(void* const* d_in, const int* in_sizes, int n_in,
                              void* d_out, int out_size, void* d_ws, size_t ws_size,
                              hipStream_t stream) {
    const float* x  = (const float*)d_in[0];
    const float* w  = (const float*)d_in[1];
    float* out      = (float*)d_out;
    const int B       = in_sizes[0] / (F_IN * T_STEPS);  // 32768
    const int nblocks = B / NB;                          // 512
    snn_fused<<<nblocks, BLOCK, 0, stream>>>(x, w, out);
}